// Round 12
// baseline (79.109 us; speedup 1.0000x reference)
//
#include <hip/hip_runtime.h>
#include <math.h>

#define EPSI 1e-8f

typedef __fp16 half2v __attribute__((ext_vector_type(2)));

__device__ __forceinline__ float frcp(float x) { return __builtin_amdgcn_rcpf(x); }

// Key-only compare-exchange: unsigned min/max (2 VALU ops after unroll).
#define CE(A, B) {                                  \
    unsigned ka = key[A], kb = key[B];              \
    key[A] = ka < kb ? ka : kb;                     \
    key[B] = ka < kb ? kb : ka; }

// 256-thread WG (4 waves), f16-packed LDS stash -> 24KB/WG, (256,4)=128-VGPR
// cap ((256,5)=102-cap spilled wholesale in R9: 110MB scratch traffic).
// Factored rectangle intersections (R11): 4 rcps, corner-in-box = sign(den).
// R12: single dispatch — per-block atomicAdd into d_out (memset-0 on stream),
// deleting the reduce kernel + its launch gap + the d_ws partial round-trip.
__global__ __launch_bounds__(256, 4) void diou3d_main(
    const float* __restrict__ pred, const float* __restrict__ tgt,
    float* __restrict__ out, float invn, int n)
{
    __shared__ unsigned vbuf[24][256];  // f16x2-packed centered coords
    __shared__ float wsum[4];
    int tx = threadIdx.x;
    int tid = blockIdx.x * 256 + tx;
    float loss = 0.0f;
    if (tid < n) {
        const float* P = pred + (size_t)tid * 7;
        const float* T = tgt  + (size_t)tid * 7;
        // two overlapping dwordx4 per row (dword-aligned, stride 28B)
        float4 Pa = *reinterpret_cast<const float4*>(P);
        float4 Pb = *reinterpret_cast<const float4*>(P + 3);
        float4 Ta = *reinterpret_cast<const float4*>(T);
        float4 Tb = *reinterpret_cast<const float4*>(T + 3);
        float p0 = Pa.x, p1 = Pa.y, p2 = Pa.z, p3 = Pb.x, p4 = Pb.y, p5 = Pb.z, p6 = Pb.w;
        float t0 = Ta.x, t1 = Ta.y, t2 = Ta.z, t3 = Tb.x, t4 = Tb.y, t5 = Tb.z, t6 = Tb.w;

        // ---- 2D corners (cols 0,1,3,4,6), CCW ----
        float sp, cp, st, ct;
        __sincosf(p6, &sp, &cp);
        __sincosf(t6, &st, &ct);
        const float hx[4] = {0.5f, -0.5f, -0.5f, 0.5f};
        const float hy[4] = {0.5f, 0.5f, -0.5f, -0.5f};
        float c1x[4], c1y[4], c2x[4], c2y[4];
#pragma unroll
        for (int k = 0; k < 4; k++) {
            float xa = hx[k] * p3, ya = hy[k] * p4;
            c1x[k] = xa * cp - ya * sp + p0;
            c1y[k] = xa * sp + ya * cp + p1;
            float xb = hx[k] * t3, yb = hy[k] * t4;
            c2x[k] = xb * ct - yb * st + t0;
            c2y[k] = xb * st + yb * ct + t1;
        }

        float vx[24], vy[24];
        float ma[24];   // mask as float (0/1)

        // corner slots 0..7
#pragma unroll
        for (int k = 0; k < 4; k++) {
            vx[k] = c1x[k];     vy[k] = c1y[k];
            vx[4 + k] = c2x[k]; vy[4 + k] = c2y[k];
        }

        // ---- factored intersections + in-box tests (verified R11) ----
        // Rectangle: edge i dir = s_i * e1[i&1], s_i = (i<2 ? +1 : -1); same for box2.
        // num[i][j]   = s_i*s_j*bnum[i&1][j&1]           (4 distinct crosses, 4 rcps)
        // t = s_i * g*rb ; u = s_j * h*rb ; point = p_i + (g*rb)*e1[i&1]
        // c1_i in box2 <=> g[i][0..1]>=0 & g[i][2..3]<=0 ; c2_j sym. in h.
        float e1x[2], e1y[2], e2x[2], e2y[2];
        e1x[0] = c1x[1] - c1x[0]; e1y[0] = c1y[1] - c1y[0];
        e1x[1] = c1x[2] - c1x[1]; e1y[1] = c1y[2] - c1y[1];
        e2x[0] = c2x[1] - c2x[0]; e2y[0] = c2y[1] - c2y[0];
        e2x[1] = c2x[2] - c2x[1]; e2y[1] = c2y[2] - c2y[1];

        float rb[2][2];
#pragma unroll
        for (int a = 0; a < 2; a++)
#pragma unroll
            for (int b = 0; b < 2; b++) {
                float bn = e2y[b] * e1x[a] - e2x[b] * e1y[a];
                rb[a][b] = frcp(bn + EPSI);
            }

        float A_[2][4], Bv[4], C_[2][4], Dv[4];
#pragma unroll
        for (int b = 0; b < 2; b++)
#pragma unroll
            for (int i = 0; i < 4; i++)
                A_[b][i] = e2x[b] * c1y[i] - e2y[b] * c1x[i];
#pragma unroll
        for (int j = 0; j < 4; j++)
            Bv[j] = e2x[j & 1] * c2y[j] - e2y[j & 1] * c2x[j];
#pragma unroll
        for (int a = 0; a < 2; a++)
#pragma unroll
            for (int j = 0; j < 4; j++)
                C_[a][j] = e1x[a] * c2y[j] - e1y[a] * c2x[j];
#pragma unroll
        for (int i = 0; i < 4; i++)
            Dv[i] = e1x[i & 1] * c1y[i] - e1y[i & 1] * c1x[i];

        float hmn[4], hmx[4];
#pragma unroll
        for (int i = 0; i < 4; i++) {
            float gmn = 0.0f, gmx = 0.0f;
#pragma unroll
            for (int j = 0; j < 4; j++) {
                const int a = i & 1, b = j & 1;
                float g = A_[b][i] - Bv[j];
                float h = C_[a][j] - Dv[i];
                float r = rb[a][b];
                float tau = g * r;
                float ups = h * r;
                bool mt = (i < 2) ? (tau > 0.0f && tau < 1.0f)
                                  : (tau > -1.0f && tau < 0.0f);
                bool mu = (j < 2) ? (ups > 0.0f && ups < 1.0f)
                                  : (ups > -1.0f && ups < 0.0f);
                const int idx = 8 + i * 4 + j;
                vx[idx] = fmaf(tau, e1x[a], c1x[i]);
                vy[idx] = fmaf(tau, e1y[a], c1y[i]);
                ma[idx] = (mt && mu) ? 1.0f : 0.0f;
                if (j == 0) gmn = g; else if (j == 1) gmn = fminf(gmn, g);
                else if (j == 2) gmx = g; else gmx = fmaxf(gmx, g);
                if (i == 0) hmn[j] = h;
                else if (i == 1) hmn[j] = fminf(hmn[j], h);
                else if (i == 2) hmx[j] = h;
                else hmx[j] = fmaxf(hmx[j], h);
            }
            ma[i] = (gmn >= 0.0f && gmx <= 0.0f) ? 1.0f : 0.0f;
        }
#pragma unroll
        for (int j = 0; j < 4; j++)
            ma[4 + j] = (hmn[j] >= 0.0f && hmx[j] <= 0.0f) ? 1.0f : 0.0f;

        // ---- centroid over valid vertices (fma form) ----
        float cntf = 0.0f, sx = 0.0f, sy = 0.0f;
#pragma unroll
        for (int k = 0; k < 24; k++) {
            cntf += ma[k];
            sx = fmaf(ma[k], vx[k], sx);
            sy = fmaf(ma[k], vy[k], sy);
        }
        int ic = (int)cntf;
        float rnv = frcp(fmaxf(cntf, 1.0f));
        float mx = sx * rnv, my = sy * rnv;

        // ---- center, stash f16-packed to LDS, build sortable uint key ----
        // key = monotone(uint(pseudoangle)) with low 5 bits = vertex index
        // (stable tie-break == reference stable argsort; invalid = 0xFFFFFFE0|k)
        unsigned key[24];
#pragma unroll
        for (int k = 0; k < 24; k++) {
            float ux = vx[k] - mx, uy = vy[k] - my;
            half2v h = __builtin_amdgcn_cvt_pkrtz(ux, uy);
            vbuf[k][tx] = __builtin_bit_cast(unsigned, h);
            float d = fabsf(ux) + fabsf(uy);
            float pq = ux * frcp(d);
            pq = (d == 0.0f) ? 0.0f : pq;
            float ang = (uy < 0.0f) ? (pq - 1.0f) : (1.0f - pq);
            unsigned u = __float_as_uint(ang);
            u ^= (unsigned)(((int)u >> 31)) | 0x80000000u;   // sortable uint
            unsigned kk = (u & 0xFFFFFFE0u) | (unsigned)k;
            key[k] = (ma[k] != 0.0f) ? kk : (0xFFFFFFE0u | (unsigned)k);
        }

        // ---- Batcher odd-even mergesort, n=32, comparators hitting idx>=24
        //      skipped (ascending CEs + virtual +inf padding never move) ----
#pragma unroll
        for (int p = 1; p < 32; p <<= 1) {
#pragma unroll
            for (int k = p; k >= 1; k >>= 1) {
#pragma unroll
                for (int j = k & (p - 1); j + k < 32; j += 2 * k) {
#pragma unroll
                    for (int i = 0; i < k; i++) {
                        int lo = i + j, hi = i + j + k;
                        if (hi < 24 && (lo / (2 * p) == hi / (2 * p))) {
                            CE(lo, hi);
                        }
                    }
                }
            }
        }

        // ---- gather first 12 sorted vertices from LDS (lane-private column;
        //      per-lane program order, no barrier; bank = tx%32, conflict-free) ----
        float gx[12], gy[12];
#pragma unroll
        for (int s = 0; s < 12; s++) {
            int idx = (int)(key[s] & 31u);
            half2v h = __builtin_bit_cast(half2v, vbuf[idx][tx]);
            gx[s] = (float)h.x; gy[s] = (float)h.y;
        }

        // ---- pad invalid slots with sorted-first, shoelace over 12 ----
        float x0 = gx[0], y0 = gy[0];
#pragma unroll
        for (int s = 0; s < 12; s++) {
            bool v = (s < ic);
            gx[s] = v ? gx[s] : x0;
            gy[s] = v ? gy[s] : y0;
        }
        float area2 = 0.0f;
#pragma unroll
        for (int s = 0; s < 12; s++) {
            int ns = (s == 11) ? 0 : s + 1;
            area2 += gx[s] * gy[ns] - gy[s] * gx[ns];
        }
        float inter2d = 0.5f * fabsf(area2);

        // ---- z-overlap, volumes, IoU ----
        float zmax1 = p2 + 0.5f * p5, zmin1 = p2 - 0.5f * p5;
        float zmax2 = t2 + 0.5f * t5, zmin2 = t2 - 0.5f * t5;
        float zov = fmaxf(fminf(zmax1, zmax2) - fmaxf(zmin1, zmin2), 0.0f);
        float inter3d = inter2d * zov;
        float vol1 = p3 * p4 * p5, vol2 = t3 * t4 * t5;
        float iou = inter3d / (vol1 + vol2 - inter3d);
        if (isnan(iou)) iou = 0.0f;   // jnp.nan_to_num(..., nan=0.0)

        // ---- center distance ----
        float d0 = p0 - t0, d1 = p1 - t1, d2 = p2 - t2;
        float ctd = d0 * d0 + d1 * d1 + d2 * d2;

        // ---- corner distance, closed form (verified rounds 2..11) ----
        float cosd = cp * ct + sp * st;   // cos(theta_p - theta_t)
        float dp2 = p3 * p3 + p4 * p4 + p5 * p5;
        float dt2 = t3 * t3 + t4 * t4 + t5 * t5;   // == did
        float crossd = p3 * t3 * cosd + p4 * t4 + p5 * t5 * cosd;
        float cnd = ctd + 0.25f * (dp2 + dt2) - 0.5f * crossd;

        float dterm = (ctd + cnd) / (ctd + cnd + dt2 + 1e-6f);
        loss = 1.0f - iou + dterm;
    }

    // ---- wave reduction, cross-wave via LDS, one atomic per block ----
#pragma unroll
    for (int off = 32; off > 0; off >>= 1) loss += __shfl_down(loss, off);
    int lane = tx & 63, wid = tx >> 6;
    if (lane == 0) wsum[wid] = loss;
    __syncthreads();
    if (tx == 0)
        atomicAdd(out, (wsum[0] + wsum[1] + wsum[2] + wsum[3]) * invn);
}

extern "C" void kernel_launch(void* const* d_in, const int* in_sizes, int n_in,
                              void* d_out, int out_size, void* d_ws, size_t ws_size,
                              hipStream_t stream) {
    const float* pred = (const float*)d_in[0];
    const float* tgt  = (const float*)d_in[1];
    float* out = (float*)d_out;
    int n = in_sizes[0] / 7;
    const int T = 256;
    int blocks = (n + T - 1) / T;
    hipMemsetAsync(out, 0, sizeof(float), stream);   // capturable; d_out re-poisoned each call
    diou3d_main<<<blocks, T, 0, stream>>>(pred, tgt, out, 1.0f / (float)n, n);
}

// Round 13
// 74.918 us; speedup vs baseline: 1.0559x; 1.0559x over previous
//
#include <hip/hip_runtime.h>
#include <math.h>

#define EPSI 1e-8f

typedef __fp16 half2v __attribute__((ext_vector_type(2)));

__device__ __forceinline__ float frcp(float x) { return __builtin_amdgcn_rcpf(x); }

// Key-only compare-exchange: unsigned min/max (2 VALU ops after unroll).
#define CE(A, B) {                                  \
    unsigned ka = key[A], kb = key[B];              \
    key[A] = ka < kb ? ka : kb;                     \
    key[B] = ka < kb ? kb : ka; }

// R13 = R11 (best verified: 75.2us, absmax 0.0) + float4 input loads.
// Two-dispatch structure is deliberate: R12's memset+per-block atomicAdd
// regressed 4us (graph-node serialization + cross-XCD cacheline ping-pong);
// a 3us reduce kernel is cheaper than 1024 device-scope atomics.
// (256,4)=128-VGPR cap: (256,5)=102-cap spilled wholesale (R9, 110MB scratch).
__global__ __launch_bounds__(256, 4) void diou3d_main(
    const float* __restrict__ pred, const float* __restrict__ tgt,
    float* __restrict__ partial, int n)
{
    __shared__ unsigned vbuf[24][256];  // f16x2-packed centered coords
    __shared__ float wsum[4];
    int tx = threadIdx.x;
    int tid = blockIdx.x * 256 + tx;
    float loss = 0.0f;
    if (tid < n) {
        const float* P = pred + (size_t)tid * 7;
        const float* T = tgt  + (size_t)tid * 7;
        // two overlapping dwordx4 per row (dword-aligned, stride 28B)
        float4 Pa = *reinterpret_cast<const float4*>(P);
        float4 Pb = *reinterpret_cast<const float4*>(P + 3);
        float4 Ta = *reinterpret_cast<const float4*>(T);
        float4 Tb = *reinterpret_cast<const float4*>(T + 3);
        float p0 = Pa.x, p1 = Pa.y, p2 = Pa.z, p3 = Pb.x, p4 = Pb.y, p5 = Pb.z, p6 = Pb.w;
        float t0 = Ta.x, t1 = Ta.y, t2 = Ta.z, t3 = Tb.x, t4 = Tb.y, t5 = Tb.z, t6 = Tb.w;

        // ---- 2D corners (cols 0,1,3,4,6), CCW ----
        float sp, cp, st, ct;
        __sincosf(p6, &sp, &cp);
        __sincosf(t6, &st, &ct);
        const float hx[4] = {0.5f, -0.5f, -0.5f, 0.5f};
        const float hy[4] = {0.5f, 0.5f, -0.5f, -0.5f};
        float c1x[4], c1y[4], c2x[4], c2y[4];
#pragma unroll
        for (int k = 0; k < 4; k++) {
            float xa = hx[k] * p3, ya = hy[k] * p4;
            c1x[k] = xa * cp - ya * sp + p0;
            c1y[k] = xa * sp + ya * cp + p1;
            float xb = hx[k] * t3, yb = hy[k] * t4;
            c2x[k] = xb * ct - yb * st + t0;
            c2y[k] = xb * st + yb * ct + t1;
        }

        float vx[24], vy[24];
        float ma[24];   // mask as float (0/1)

        // corner slots 0..7
#pragma unroll
        for (int k = 0; k < 4; k++) {
            vx[k] = c1x[k];     vy[k] = c1y[k];
            vx[4 + k] = c2x[k]; vy[4 + k] = c2y[k];
        }

        // ---- factored intersections + in-box tests (verified R11) ----
        // Rectangle: edge i dir = s_i * e1[i&1], s_i = (i<2 ? +1 : -1); same for box2.
        // num[i][j]   = s_i*s_j*bnum[i&1][j&1]           (4 distinct crosses, 4 rcps)
        // t = s_i * g*rb ; u = s_j * h*rb ; point = p_i + (g*rb)*e1[i&1]
        // c1_i in box2 <=> g[i][0..1]>=0 & g[i][2..3]<=0 ; c2_j sym. in h.
        float e1x[2], e1y[2], e2x[2], e2y[2];
        e1x[0] = c1x[1] - c1x[0]; e1y[0] = c1y[1] - c1y[0];
        e1x[1] = c1x[2] - c1x[1]; e1y[1] = c1y[2] - c1y[1];
        e2x[0] = c2x[1] - c2x[0]; e2y[0] = c2y[1] - c2y[0];
        e2x[1] = c2x[2] - c2x[1]; e2y[1] = c2y[2] - c2y[1];

        float rb[2][2];
#pragma unroll
        for (int a = 0; a < 2; a++)
#pragma unroll
            for (int b = 0; b < 2; b++) {
                float bn = e2y[b] * e1x[a] - e2x[b] * e1y[a];
                rb[a][b] = frcp(bn + EPSI);
            }

        float A_[2][4], Bv[4], C_[2][4], Dv[4];
#pragma unroll
        for (int b = 0; b < 2; b++)
#pragma unroll
            for (int i = 0; i < 4; i++)
                A_[b][i] = e2x[b] * c1y[i] - e2y[b] * c1x[i];
#pragma unroll
        for (int j = 0; j < 4; j++)
            Bv[j] = e2x[j & 1] * c2y[j] - e2y[j & 1] * c2x[j];
#pragma unroll
        for (int a = 0; a < 2; a++)
#pragma unroll
            for (int j = 0; j < 4; j++)
                C_[a][j] = e1x[a] * c2y[j] - e1y[a] * c2x[j];
#pragma unroll
        for (int i = 0; i < 4; i++)
            Dv[i] = e1x[i & 1] * c1y[i] - e1y[i & 1] * c1x[i];

        float hmn[4], hmx[4];
#pragma unroll
        for (int i = 0; i < 4; i++) {
            float gmn = 0.0f, gmx = 0.0f;
#pragma unroll
            for (int j = 0; j < 4; j++) {
                const int a = i & 1, b = j & 1;
                float g = A_[b][i] - Bv[j];
                float h = C_[a][j] - Dv[i];
                float r = rb[a][b];
                float tau = g * r;
                float ups = h * r;
                bool mt = (i < 2) ? (tau > 0.0f && tau < 1.0f)
                                  : (tau > -1.0f && tau < 0.0f);
                bool mu = (j < 2) ? (ups > 0.0f && ups < 1.0f)
                                  : (ups > -1.0f && ups < 0.0f);
                const int idx = 8 + i * 4 + j;
                vx[idx] = fmaf(tau, e1x[a], c1x[i]);
                vy[idx] = fmaf(tau, e1y[a], c1y[i]);
                ma[idx] = (mt && mu) ? 1.0f : 0.0f;
                if (j == 0) gmn = g; else if (j == 1) gmn = fminf(gmn, g);
                else if (j == 2) gmx = g; else gmx = fmaxf(gmx, g);
                if (i == 0) hmn[j] = h;
                else if (i == 1) hmn[j] = fminf(hmn[j], h);
                else if (i == 2) hmx[j] = h;
                else hmx[j] = fmaxf(hmx[j], h);
            }
            ma[i] = (gmn >= 0.0f && gmx <= 0.0f) ? 1.0f : 0.0f;
        }
#pragma unroll
        for (int j = 0; j < 4; j++)
            ma[4 + j] = (hmn[j] >= 0.0f && hmx[j] <= 0.0f) ? 1.0f : 0.0f;

        // ---- centroid over valid vertices (fma form) ----
        float cntf = 0.0f, sx = 0.0f, sy = 0.0f;
#pragma unroll
        for (int k = 0; k < 24; k++) {
            cntf += ma[k];
            sx = fmaf(ma[k], vx[k], sx);
            sy = fmaf(ma[k], vy[k], sy);
        }
        int ic = (int)cntf;
        float rnv = frcp(fmaxf(cntf, 1.0f));
        float mx = sx * rnv, my = sy * rnv;

        // ---- center, stash f16-packed to LDS, build sortable uint key ----
        // key = monotone(uint(pseudoangle)) with low 5 bits = vertex index
        // (stable tie-break == reference stable argsort; invalid = 0xFFFFFFE0|k)
        unsigned key[24];
#pragma unroll
        for (int k = 0; k < 24; k++) {
            float ux = vx[k] - mx, uy = vy[k] - my;
            half2v h = __builtin_amdgcn_cvt_pkrtz(ux, uy);
            vbuf[k][tx] = __builtin_bit_cast(unsigned, h);
            float d = fabsf(ux) + fabsf(uy);
            float pq = ux * frcp(d);
            pq = (d == 0.0f) ? 0.0f : pq;
            float ang = (uy < 0.0f) ? (pq - 1.0f) : (1.0f - pq);
            unsigned u = __float_as_uint(ang);
            u ^= (unsigned)(((int)u >> 31)) | 0x80000000u;   // sortable uint
            unsigned kk = (u & 0xFFFFFFE0u) | (unsigned)k;
            key[k] = (ma[k] != 0.0f) ? kk : (0xFFFFFFE0u | (unsigned)k);
        }

        // ---- Batcher odd-even mergesort, n=32, comparators hitting idx>=24
        //      skipped (ascending CEs + virtual +inf padding never move) ----
#pragma unroll
        for (int p = 1; p < 32; p <<= 1) {
#pragma unroll
            for (int k = p; k >= 1; k >>= 1) {
#pragma unroll
                for (int j = k & (p - 1); j + k < 32; j += 2 * k) {
#pragma unroll
                    for (int i = 0; i < k; i++) {
                        int lo = i + j, hi = i + j + k;
                        if (hi < 24 && (lo / (2 * p) == hi / (2 * p))) {
                            CE(lo, hi);
                        }
                    }
                }
            }
        }

        // ---- gather first 12 sorted vertices from LDS (lane-private column;
        //      per-lane program order, no barrier; bank = tx%32, conflict-free) ----
        float gx[12], gy[12];
#pragma unroll
        for (int s = 0; s < 12; s++) {
            int idx = (int)(key[s] & 31u);
            half2v h = __builtin_bit_cast(half2v, vbuf[idx][tx]);
            gx[s] = (float)h.x; gy[s] = (float)h.y;
        }

        // ---- pad invalid slots with sorted-first, shoelace over 12 ----
        float x0 = gx[0], y0 = gy[0];
#pragma unroll
        for (int s = 0; s < 12; s++) {
            bool v = (s < ic);
            gx[s] = v ? gx[s] : x0;
            gy[s] = v ? gy[s] : y0;
        }
        float area2 = 0.0f;
#pragma unroll
        for (int s = 0; s < 12; s++) {
            int ns = (s == 11) ? 0 : s + 1;
            area2 += gx[s] * gy[ns] - gy[s] * gx[ns];
        }
        float inter2d = 0.5f * fabsf(area2);

        // ---- z-overlap, volumes, IoU ----
        float zmax1 = p2 + 0.5f * p5, zmin1 = p2 - 0.5f * p5;
        float zmax2 = t2 + 0.5f * t5, zmin2 = t2 - 0.5f * t5;
        float zov = fmaxf(fminf(zmax1, zmax2) - fmaxf(zmin1, zmin2), 0.0f);
        float inter3d = inter2d * zov;
        float vol1 = p3 * p4 * p5, vol2 = t3 * t4 * t5;
        float iou = inter3d / (vol1 + vol2 - inter3d);
        if (isnan(iou)) iou = 0.0f;   // jnp.nan_to_num(..., nan=0.0)

        // ---- center distance ----
        float d0 = p0 - t0, d1 = p1 - t1, d2 = p2 - t2;
        float ctd = d0 * d0 + d1 * d1 + d2 * d2;

        // ---- corner distance, closed form (verified rounds 2..12) ----
        float cosd = cp * ct + sp * st;   // cos(theta_p - theta_t)
        float dp2 = p3 * p3 + p4 * p4 + p5 * p5;
        float dt2 = t3 * t3 + t4 * t4 + t5 * t5;   // == did
        float crossd = p3 * t3 * cosd + p4 * t4 + p5 * t5 * cosd;
        float cnd = ctd + 0.25f * (dp2 + dt2) - 0.5f * crossd;

        float dterm = (ctd + cnd) / (ctd + cnd + dt2 + 1e-6f);
        loss = 1.0f - iou + dterm;
    }

    // ---- wave reduction, then cross-wave via LDS ----
#pragma unroll
    for (int off = 32; off > 0; off >>= 1) loss += __shfl_down(loss, off);
    int lane = tx & 63, wid = tx >> 6;
    if (lane == 0) wsum[wid] = loss;
    __syncthreads();
    if (tx == 0)
        partial[blockIdx.x] = wsum[0] + wsum[1] + wsum[2] + wsum[3];
}

__global__ __launch_bounds__(256) void diou3d_reduce(
    const float* __restrict__ partial, int nblocks, float* __restrict__ out, float invn)
{
    float s = 0.0f;
    for (int i = threadIdx.x; i < nblocks; i += 256) s += partial[i];
#pragma unroll
    for (int off = 32; off > 0; off >>= 1) s += __shfl_down(s, off);
    __shared__ float wsum[4];
    int lane = threadIdx.x & 63, wid = threadIdx.x >> 6;
    if (lane == 0) wsum[wid] = s;
    __syncthreads();
    if (threadIdx.x == 0)
        out[0] = (wsum[0] + wsum[1] + wsum[2] + wsum[3]) * invn;
}

extern "C" void kernel_launch(void* const* d_in, const int* in_sizes, int n_in,
                              void* d_out, int out_size, void* d_ws, size_t ws_size,
                              hipStream_t stream) {
    const float* pred = (const float*)d_in[0];
    const float* tgt  = (const float*)d_in[1];
    float* out = (float*)d_out;
    int n = in_sizes[0] / 7;
    const int T = 256;
    int blocks = (n + T - 1) / T;
    float* partial = (float*)d_ws;   // fully written each call (poison-safe)
    diou3d_main<<<blocks, T, 0, stream>>>(pred, tgt, partial, n);
    diou3d_reduce<<<1, 256, 0, stream>>>(partial, blocks, out, 1.0f / (float)n);
}